// Round 10
// baseline (311.718 us; speedup 1.0000x reference)
//
#include <hip/hip_runtime.h>
#include <math.h>

#define N_VOX 200000
#define CCH   128
#define KOFF  27
#define NSTEPS 54   // 27 offsets x 2 BK=64 halves

typedef __attribute__((ext_vector_type(8))) short bf16x8;
typedef __attribute__((ext_vector_type(4))) float f32x4;

__device__ __forceinline__ float silu_f(float x) {
    return x / (1.0f + expf(-x));
}
__device__ __forceinline__ unsigned short f2bf(float x) {
    unsigned int u = __float_as_uint(x);
    u = (u + 0x7FFFu + ((u >> 16) & 1u)) >> 16;
    return (unsigned short)u;
}
// bijective XCD-aware block swizzle (m204 variant)
__device__ __forceinline__ int xcd_swz(int orig, int nwg) {
    int q = nwg >> 3, r = nwg & 7;
    int xcd = orig & 7, pos = orig >> 3;
    return (xcd < r ? xcd * (q + 1) : r * (q + 1) + (xcd - r) * q) + pos;
}
// async 16B global -> LDS (direct-to-shared DMA)
__device__ __forceinline__ void gload_lds16(const void* g, void* l) {
    __builtin_amdgcn_global_load_lds(
        (const __attribute__((address_space(1))) unsigned int*)g,
        (__attribute__((address_space(3))) unsigned int*)l, 16, 0, 0);
}

// ---------------------------------------------------------------------------
// Kernel 1: time embedding -> bf16 xeb[(N+1)][8] = {feat, sin*3, cos*3, 0}
// ---------------------------------------------------------------------------
__global__ void embed_kernel(const float* __restrict__ feat,
                             const int* __restrict__ t,
                             unsigned short* __restrict__ xeb) {
    int i = blockIdx.x * blockDim.x + threadIdx.x;
    if (i > N_VOX) return;
    union { unsigned short u[8]; int4 v; } o;
    if (i == N_VOX) {
        o.v = make_int4(0, 0, 0, 0);
    } else {
        o.u[0] = f2bf(feat[i]);
        float tf = (float)t[i];
#pragma unroll
        for (int kk = 0; kk < 3; ++kk) {
            float freq = (float)M_PI * (float)(1 << kk);
            float ang = tf * freq;
            o.u[1 + kk] = f2bf(sinf(ang));
            o.u[4 + kk] = f2bf(cosf(ang));
        }
        o.u[7] = 0;
    }
    *(int4*)(xeb + (size_t)i * 8) = o.v;
}

// ---------------------------------------------------------------------------
// Weight repacks to MFMA-fragment-linear bf16 (B-operand layout).
// ---------------------------------------------------------------------------
__global__ void convert_w1(const float* __restrict__ W1,
                           unsigned short* __restrict__ W1f) {
    int g = blockIdx.x * 256 + threadIdx.x;
    if (g >= 7 * 8 * 64) return;
    int l = g & 63;
    int rest = g >> 6;
    int nf = rest & 7;
    int kk = rest >> 3;
    int o = kk * 4 + (l >> 4);
    int co = nf * 16 + (l & 15);
    union { unsigned short u[8]; int4 v; } out;
#pragma unroll
    for (int j = 0; j < 8; ++j) {
        float w = 0.f;
        if (o < KOFF && j < 7) w = W1[((size_t)o * 7 + j) * CCH + co];
        out.u[j] = f2bf(w);
    }
    *(int4*)(W1f + (size_t)g * 8) = out.v;
}

__global__ void convert_w2(const float* __restrict__ W2,
                           unsigned short* __restrict__ W2f) {
    int g = blockIdx.x * 256 + threadIdx.x;
    int l = g & 63;
    int rest = g >> 6;
    int nf = rest & 7;
    int kkk = rest >> 3;
    int k = kkk >> 2, kk = kkk & 3;
    int ci0 = kk * 32 + (l >> 4) * 8;
    int co = nf * 16 + (l & 15);
    union { unsigned short u[8]; int4 v; } out;
#pragma unroll
    for (int j = 0; j < 8; ++j)
        out.u[j] = f2bf(W2[((size_t)k * CCH + ci0 + j) * CCH + co]);
    *(int4*)(W2f + (size_t)g * 8) = out.v;
}

__global__ void convert_w3(const float* __restrict__ W3,
                           unsigned short* __restrict__ W3f) {
    int g = blockIdx.x * 256 + threadIdx.x;
    if (g >= 4 * 8 * 64) return;
    int l = g & 63;
    int rest = g >> 6;
    int nf = rest & 7;
    int kk = rest >> 3;
    int ci0 = kk * 32 + (l >> 4) * 8;
    int co = nf * 16 + (l & 15);
    union { unsigned short u[8]; int4 v; } out;
#pragma unroll
    for (int j = 0; j < 8; ++j)
        out.u[j] = f2bf(W3[(size_t)(ci0 + j) * CCH + co]);
    *(int4*)(W3f + (size_t)g * 8) = out.v;
}

// ---------------------------------------------------------------------------
// Kernel 2: conv1 via MFMA. 128 vox x 128 ch per block, K = 7 steps of 32.
// ---------------------------------------------------------------------------
__global__ __launch_bounds__(256) void conv1_mfma(
    const unsigned short* __restrict__ xeb, const int* __restrict__ nidx,
    const unsigned short* __restrict__ W1f, const float* __restrict__ b1,
    unsigned short* __restrict__ h1b) {
    __shared__ int4 bufmem[2048];
    __shared__ int idxAll[128 * 28];

    int tid = threadIdx.x;
    int l = tid & 63, w = tid >> 6;
    int mw = w >> 1, nwv = w & 1;
    int wg = xcd_swz(blockIdx.x, gridDim.x);
    int v0 = wg * 128;

    for (int g = tid; g < KOFF * 128; g += 256) {
        int k = g >> 7, vi = g & 127;
        int v = v0 + vi;
        idxAll[vi * 28 + k] = (v < N_VOX) ? nidx[(size_t)k * N_VOX + v] : N_VOX;
    }
    if (tid < 128) idxAll[tid * 28 + 27] = N_VOX;
    __syncthreads();

    f32x4 acc[4][4];
#pragma unroll
    for (int m = 0; m < 4; ++m)
#pragma unroll
        for (int n = 0; n < 4; ++n) acc[m][n] = (f32x4)0.f;

    {
        int4 g0[2]; int rr[2], cc[2];
#pragma unroll
        for (int u = 0; u < 2; ++u) {
            int q = u * 256 + tid;
            int r = q >> 2, oo = q & 3;
            int idx = idxAll[r * 28 + oo];
            g0[u] = *(const int4*)(xeb + (size_t)idx * 8);
            rr[u] = r; cc[u] = oo ^ (r & 3);
        }
#pragma unroll
        for (int u = 0; u < 2; ++u) bufmem[rr[u] * 5 + cc[u]] = g0[u];
    }
    __syncthreads();

    for (int kk = 0; kk < 7; ++kk) {
        int cur = kk & 1;
        int4 gg[2]; int rr[2], cc[2];
        if (kk < 6) {
#pragma unroll
            for (int u = 0; u < 2; ++u) {
                int q = u * 256 + tid;
                int r = q >> 2, oo = q & 3;
                int idx = idxAll[r * 28 + (kk + 1) * 4 + oo];
                gg[u] = *(const int4*)(xeb + (size_t)idx * 8);
                rr[u] = r; cc[u] = oo ^ (r & 3);
            }
        }
        bf16x8 a[4], b[4];
#pragma unroll
        for (int n = 0; n < 4; ++n) {
            int nf = nwv * 4 + n;
            b[n] = *(const bf16x8*)(W1f + ((size_t)(kk * 8 + nf) * 64 + l) * 8);
        }
#pragma unroll
        for (int m = 0; m < 4; ++m) {
            int r = mw * 64 + m * 16 + (l & 15);
            int c = l >> 4;
            a[m] = *(const bf16x8*)&bufmem[cur * 640 + r * 5 + (c ^ (r & 3))];
        }
#pragma unroll
        for (int m = 0; m < 4; ++m)
#pragma unroll
            for (int n = 0; n < 4; ++n)
                acc[m][n] = __builtin_amdgcn_mfma_f32_16x16x32_bf16(
                    a[m], b[n], acc[m][n], 0, 0, 0);
        if (kk < 6) {
#pragma unroll
            for (int u = 0; u < 2; ++u)
                bufmem[(cur ^ 1) * 640 + rr[u] * 5 + cc[u]] = gg[u];
        }
        __syncthreads();
    }

    float bias[4];
#pragma unroll
    for (int n = 0; n < 4; ++n) bias[n] = b1[nwv * 64 + n * 16 + (l & 15)];
    unsigned short* H16 = (unsigned short*)bufmem;
#pragma unroll
    for (int m = 0; m < 4; ++m) {
        int rbase = mw * 64 + m * 16 + (l >> 4) * 4;
#pragma unroll
        for (int n = 0; n < 4; ++n) {
            int ch = nwv * 64 + n * 16 + (l & 15);
            int c = ch >> 3;
            f32x4 d = acc[m][n];
#pragma unroll
            for (int ri = 0; ri < 4; ++ri) {
                int r = rbase + ri;
                int s = (c & 8) | ((c & 7) ^ (r & 7));
                H16[r * 128 + s * 8 + (ch & 7)] = f2bf(silu_f(d[ri] + bias[n]));
            }
        }
    }
    __syncthreads();
#pragma unroll
    for (int u = 0; u < 8; ++u) {
        int q = u * 256 + tid;
        int r = q >> 4, s = q & 15;
        int c = (s & 8) | ((s & 7) ^ (r & 7));
        int v = v0 + r;
        if (v < N_VOX)
            *(int4*)(h1b + (size_t)v * CCH + c * 8) = bufmem[r * 16 + s];
    }
    if (blockIdx.x == 0 && tid < 16)
        *(int4*)(h1b + (size_t)N_VOX * CCH + tid * 8) = make_int4(0, 0, 0, 0);
}

// ---------------------------------------------------------------------------
// Kernel 3: conv2 depth-3 pipeline + fused tail. 54 BK=64 steps; per step:
// vmcnt(4) -> s_barrier -> B(t+1)->regs(8) -> A(t+2)->gload_lds(4, 3-deep
// rotation) -> compute(8 frag-linear ds_read + 32 MFMA, setprio). The wait
// leaves exactly the 4 newest A-stages in flight (NEVER drains to 0); A has
// ~2 steps of latency budget, B one. Post-barrier staging => rotation is
// race-free. Frag-tiled LDS (slot l = lane l) => zero-conflict ds_read_b128.
// ---------------------------------------------------------------------------
#define STAGE1(dst, kh, IDX, U) {                                          \
    gload_lds16((const char*)h1b + ((size_t)(unsigned)(IDX) << 8) +        \
                    ((kh) << 7) + ((w & 1) << 6) + (hi << 4),              \
                (void*)&(dst)[((U) * 4 + w) * 64 + l]);                    \
}
#define STAGE4(dst, kh, i4) {                                              \
    STAGE1(dst, kh, (i4).x, 0); STAGE1(dst, kh, (i4).y, 1);                \
    STAGE1(dst, kh, (i4).z, 2); STAGE1(dst, kh, (i4).w, 3);                \
}

#define LOADB8(dst, stp) {                                                 \
    const unsigned short* _wb = W2f +                                      \
        (size_t)(((stp) >> 1) * 4 + ((stp) & 1) * 2) * 4096;               \
    _Pragma("unroll") for (int _kk = 0; _kk < 2; ++_kk)                    \
        _Pragma("unroll") for (int _n = 0; _n < 4; ++_n)                   \
            dst[_kk][_n] = *(const bf16x8*)(_wb +                          \
                ((size_t)(_kk * 8 + nwv * 4 + _n) * 64 + l) * 8);          \
}

#define COMPUTE(src, br) {                                                 \
    bf16x8 _a[2][4];                                                       \
    _Pragma("unroll") for (int _kk = 0; _kk < 2; ++_kk)                    \
        _Pragma("unroll") for (int _m = 0; _m < 4; ++_m)                   \
            _a[_kk][_m] = *(const bf16x8*)                                 \
                &(src)[(((mw * 4 + _m) * 2 + _kk) << 6) + l];              \
    __builtin_amdgcn_s_setprio(1);                                         \
    _Pragma("unroll") for (int _kk = 0; _kk < 2; ++_kk)                    \
        _Pragma("unroll") for (int _m = 0; _m < 4; ++_m)                   \
            _Pragma("unroll") for (int _n = 0; _n < 4; ++_n)               \
                acc[_m][_n] = __builtin_amdgcn_mfma_f32_16x16x32_bf16(     \
                    _a[_kk][_m], br[_kk][_n], acc[_m][_n], 0, 0, 0);       \
    __builtin_amdgcn_s_setprio(0);                                         \
}

__global__ __launch_bounds__(256, 2) void conv2_mfma(
    const unsigned short* __restrict__ h1b, const int* __restrict__ nidx,
    const unsigned short* __restrict__ W2f, const float* __restrict__ b2,
    const unsigned short* __restrict__ W3f, const float* __restrict__ b3,
    const float* __restrict__ W4, const float* __restrict__ b4,
    float* __restrict__ out) {
    __shared__ int4 Abuf[3 * 1024];      // 3 x 16 KB A buffers
    __shared__ int idxT[16 * 2 * 29 * 4]; // [lo][w2][k(pad29)][u], 14.5 KB

    int tid = threadIdx.x;
    int l = tid & 63, w = tid >> 6;
    int mw = w >> 1, nwv = w & 1;
    int lo = l & 15, hi = l >> 4;
    int wg = xcd_swz(blockIdx.x, gridDim.x);
    int v0 = wg * 128;

    // build idxT: row (u*2+w2)*16+lo at offset k (k=27 -> sentinel pad)
    for (int g = tid; g < 28 * 128; g += 256) {
        int k = g >> 7, vi = g & 127;
        int lo_ = vi & 15, grp = vi >> 4;   // grp = u*2 + w2
        int v = v0 + vi;
        idxT[((lo_ * 2 + (grp & 1)) * 29 + k) * 4 + (grp >> 1)] =
            (k < KOFF && v < N_VOX) ? nidx[(size_t)k * N_VOX + v] : N_VOX;
    }
    __syncthreads();

    f32x4 acc[4][4];
#pragma unroll
    for (int m = 0; m < 4; ++m)
#pragma unroll
        for (int n = 0; n < 4; ++n) acc[m][n] = (f32x4)0.f;

    const int* myidx = &idxT[(lo * 2 + mw) * 29 * 4];
    bf16x8 bX[2][4], bY[2][4];
    int4* P0 = &Abuf[0];
    int4* P1 = &Abuf[1024];
    int4* P2 = &Abuf[2048];

    // prologue: A(0), B(0), A(1) in this exact order; i4cur <- k=1
    int4 i4cur = *(const int4*)&myidx[0];
    STAGE4(P0, 0, i4cur);
    __builtin_amdgcn_sched_barrier(0);
    LOADB8(bX, 0);
    __builtin_amdgcn_sched_barrier(0);
    STAGE4(P1, 1, i4cur);
    __builtin_amdgcn_sched_barrier(0);
    i4cur = *(const int4*)&myidx[4];

    for (int tp = 0; tp < NSTEPS; tp += 2) {
        int k2 = (tp >> 1) + 1;
        int kn = (k2 + 1 < 28) ? k2 + 1 : 27;
        // ---- body A (step tp, kh of staged = 0) ----
        asm volatile("s_waitcnt vmcnt(4)" ::: "memory");
        __builtin_amdgcn_s_barrier();
        int4 i4next = *(const int4*)&myidx[kn * 4];
        LOADB8(bY, tp + 1);
        __builtin_amdgcn_sched_barrier(0);
        STAGE4(P2, 0, i4cur);
        __builtin_amdgcn_sched_barrier(0);
        COMPUTE(P0, bX);
        // ---- body B (step tp+1, kh of staged = 1) ----
        asm volatile("s_waitcnt vmcnt(4)" ::: "memory");
        __builtin_amdgcn_s_barrier();
        LOADB8(bX, tp + 2);
        __builtin_amdgcn_sched_barrier(0);
        STAGE4(P0, 1, i4cur);
        __builtin_amdgcn_sched_barrier(0);
        COMPUTE(P1, bY);
        // rotate buffers: (P0,P1,P2) <- (P2,P0,P1)
        int4* tmp = P0; P0 = P2; P2 = P1; P1 = tmp;
        i4cur = i4next;
    }
    asm volatile("s_waitcnt vmcnt(0)" ::: "memory");
    __syncthreads();

    // ---- fused tail: H = bf16(silu(acc+b2)) -> LDS; P = H @ W3; out ----
    float bias2[4];
#pragma unroll
    for (int n = 0; n < 4; ++n) bias2[n] = b2[nwv * 64 + n * 16 + (l & 15)];
    unsigned short* H16 = (unsigned short*)&Abuf[0];
#pragma unroll
    for (int m = 0; m < 4; ++m) {
        int rbase = mw * 64 + m * 16 + (l >> 4) * 4;
#pragma unroll
        for (int n = 0; n < 4; ++n) {
            int ch = nwv * 64 + n * 16 + (l & 15);
            int c = ch >> 3;
            f32x4 d = acc[m][n];
#pragma unroll
            for (int ri = 0; ri < 4; ++ri) {
                int r = rbase + ri;
                int s = (c & 8) | ((c & 7) ^ (r & 7));
                H16[r * 128 + s * 8 + (ch & 7)] = f2bf(silu_f(d[ri] + bias2[n]));
            }
        }
    }
    __syncthreads();

    f32x4 p[4][4];
#pragma unroll
    for (int m = 0; m < 4; ++m)
#pragma unroll
        for (int n = 0; n < 4; ++n) p[m][n] = (f32x4)0.f;
#pragma unroll
    for (int kk = 0; kk < 4; ++kk) {
        bf16x8 a[4], b[4];
#pragma unroll
        for (int n = 0; n < 4; ++n) {
            int nf = nwv * 4 + n;
            b[n] = *(const bf16x8*)(W3f + ((size_t)(kk * 8 + nf) * 64 + l) * 8);
        }
#pragma unroll
        for (int m = 0; m < 4; ++m) {
            int r = mw * 64 + m * 16 + (l & 15);
            int c = kk * 4 + (l >> 4);
            int s = (c & 8) | ((c & 7) ^ (r & 7));
            a[m] = *(const bf16x8*)&H16[r * 128 + s * 8];
        }
#pragma unroll
        for (int m = 0; m < 4; ++m)
#pragma unroll
            for (int n = 0; n < 4; ++n)
                p[m][n] = __builtin_amdgcn_mfma_f32_16x16x32_bf16(
                    a[m], b[n], p[m][n], 0, 0, 0);
    }

    float w4v[4], b3v[4];
#pragma unroll
    for (int n = 0; n < 4; ++n) {
        int ch = nwv * 64 + n * 16 + (l & 15);
        w4v[n] = W4[ch];
        b3v[n] = b3[ch];
    }
    float* Osum = (float*)idxT;
#pragma unroll
    for (int m = 0; m < 4; ++m) {
        float po[4] = {0.f, 0.f, 0.f, 0.f};
#pragma unroll
        for (int n = 0; n < 4; ++n) {
            f32x4 d = p[m][n];
#pragma unroll
            for (int ri = 0; ri < 4; ++ri)
                po[ri] += silu_f(d[ri] + b3v[n]) * w4v[n];
        }
#pragma unroll
        for (int off = 1; off < 16; off <<= 1)
#pragma unroll
            for (int ri = 0; ri < 4; ++ri)
                po[ri] += __shfl_xor(po[ri], off, 64);
        if ((l & 15) == 0) {
            int rbase = mw * 64 + m * 16 + (l >> 4) * 4;
#pragma unroll
            for (int ri = 0; ri < 4; ++ri)
                Osum[nwv * 128 + rbase + ri] = po[ri];
        }
    }
    __syncthreads();
    if (tid < 128) {
        int v = v0 + tid;
        if (v < N_VOX) out[v] = Osum[tid] + Osum[128 + tid] + b4[0];
    }
}

// ---------------------------------------------------------------------------
extern "C" void kernel_launch(void* const* d_in, const int* in_sizes, int n_in,
                              void* d_out, int out_size, void* d_ws,
                              size_t ws_size, hipStream_t stream) {
    const float* feat = (const float*)d_in[0];
    const int* t      = (const int*)d_in[1];
    const int* nidx   = (const int*)d_in[2];
    const float* W1   = (const float*)d_in[3];
    const float* b1   = (const float*)d_in[4];
    const float* W2   = (const float*)d_in[5];
    const float* b2   = (const float*)d_in[6];
    const float* W3   = (const float*)d_in[7];
    const float* b3   = (const float*)d_in[8];
    const float* W4   = (const float*)d_in[9];
    const float* b4   = (const float*)d_in[10];
    float* out = (float*)d_out;

    char* ws = (char*)d_ws;
    size_t off = 0;
    unsigned short* xeb = (unsigned short*)(ws + off);
    off += ((size_t)(N_VOX + 1) * 8 * 2 + 255) & ~(size_t)255;
    unsigned short* h1b = (unsigned short*)(ws + off);
    off += ((size_t)(N_VOX + 1) * CCH * 2 + 255) & ~(size_t)255;
    unsigned short* W1f = (unsigned short*)(ws + off);
    off += ((size_t)7 * 8 * 64 * 8 * 2 + 255) & ~(size_t)255;
    unsigned short* W2f = (unsigned short*)(ws + off);
    // 28 k-slots (slot 27 = pad read by the pipeline tail, values unused)
    off += ((size_t)(KOFF + 1) * 4 * 8 * 64 * 8 * 2 + 255) & ~(size_t)255;
    unsigned short* W3f = (unsigned short*)(ws + off);

    int grid1 = (N_VOX + 127) / 128;
    int grid2 = (N_VOX + 127) / 128;
    embed_kernel<<<(N_VOX + 1 + 255) / 256, 256, 0, stream>>>(feat, t, xeb);
    convert_w1<<<(7 * 8 * 64 + 255) / 256, 256, 0, stream>>>(W1, W1f);
    convert_w2<<<(KOFF * 4 * 8 * 64) / 256, 256, 0, stream>>>(W2, W2f);
    convert_w3<<<(4 * 8 * 64 + 255) / 256, 256, 0, stream>>>(W3, W3f);
    conv1_mfma<<<grid1, 256, 0, stream>>>(xeb, nidx, W1f, b1, h1b);
    conv2_mfma<<<grid2, 256, 0, stream>>>(h1b, nidx, W2f, b2, W3f, b3, W4, b4, out);
}

// Round 11
// 304.883 us; speedup vs baseline: 1.0224x; 1.0224x over previous
//
#include <hip/hip_runtime.h>
#include <math.h>

#define N_VOX 200000
#define CCH   128
#define KOFF  27

typedef __attribute__((ext_vector_type(8))) short bf16x8;
typedef __attribute__((ext_vector_type(4))) float f32x4;

__device__ __forceinline__ float silu_f(float x) {
    return x / (1.0f + expf(-x));
}
__device__ __forceinline__ unsigned short f2bf(float x) {
    unsigned int u = __float_as_uint(x);
    u = (u + 0x7FFFu + ((u >> 16) & 1u)) >> 16;
    return (unsigned short)u;
}
// bijective XCD-aware block swizzle (m204 variant)
__device__ __forceinline__ int xcd_swz(int orig, int nwg) {
    int q = nwg >> 3, r = nwg & 7;
    int xcd = orig & 7, pos = orig >> 3;
    return (xcd < r ? xcd * (q + 1) : r * (q + 1) + (xcd - r) * q) + pos;
}
// async 16B global -> LDS (direct-to-shared DMA)
__device__ __forceinline__ void gload_lds16(const void* g, void* l) {
    __builtin_amdgcn_global_load_lds(
        (const __attribute__((address_space(1))) unsigned int*)g,
        (__attribute__((address_space(3))) unsigned int*)l, 16, 0, 0);
}

// ---------------------------------------------------------------------------
// Kernel 1: time embedding -> bf16 xeb[(N+1)][8] = {feat, sin*3, cos*3, 0}
// ---------------------------------------------------------------------------
__global__ void embed_kernel(const float* __restrict__ feat,
                             const int* __restrict__ t,
                             unsigned short* __restrict__ xeb) {
    int i = blockIdx.x * blockDim.x + threadIdx.x;
    if (i > N_VOX) return;
    union { unsigned short u[8]; int4 v; } o;
    if (i == N_VOX) {
        o.v = make_int4(0, 0, 0, 0);
    } else {
        o.u[0] = f2bf(feat[i]);
        float tf = (float)t[i];
#pragma unroll
        for (int kk = 0; kk < 3; ++kk) {
            float freq = (float)M_PI * (float)(1 << kk);
            float ang = tf * freq;
            o.u[1 + kk] = f2bf(sinf(ang));
            o.u[4 + kk] = f2bf(cosf(ang));
        }
        o.u[7] = 0;
    }
    *(int4*)(xeb + (size_t)i * 8) = o.v;
}

// ---------------------------------------------------------------------------
// Weight repacks to MFMA-fragment-linear bf16 (B-operand layout).
// ---------------------------------------------------------------------------
__global__ void convert_w1(const float* __restrict__ W1,
                           unsigned short* __restrict__ W1f) {
    int g = blockIdx.x * 256 + threadIdx.x;
    if (g >= 7 * 8 * 64) return;
    int l = g & 63;
    int rest = g >> 6;
    int nf = rest & 7;
    int kk = rest >> 3;
    int o = kk * 4 + (l >> 4);
    int co = nf * 16 + (l & 15);
    union { unsigned short u[8]; int4 v; } out;
#pragma unroll
    for (int j = 0; j < 8; ++j) {
        float w = 0.f;
        if (o < KOFF && j < 7) w = W1[((size_t)o * 7 + j) * CCH + co];
        out.u[j] = f2bf(w);
    }
    *(int4*)(W1f + (size_t)g * 8) = out.v;
}

__global__ void convert_w2(const float* __restrict__ W2,
                           unsigned short* __restrict__ W2f) {
    int g = blockIdx.x * 256 + threadIdx.x;
    int l = g & 63;
    int rest = g >> 6;
    int nf = rest & 7;
    int kkk = rest >> 3;
    int k = kkk >> 2, kk = kkk & 3;
    int ci0 = kk * 32 + (l >> 4) * 8;
    int co = nf * 16 + (l & 15);
    union { unsigned short u[8]; int4 v; } out;
#pragma unroll
    for (int j = 0; j < 8; ++j)
        out.u[j] = f2bf(W2[((size_t)k * CCH + ci0 + j) * CCH + co]);
    *(int4*)(W2f + (size_t)g * 8) = out.v;
}

__global__ void convert_w3(const float* __restrict__ W3,
                           unsigned short* __restrict__ W3f) {
    int g = blockIdx.x * 256 + threadIdx.x;
    if (g >= 4 * 8 * 64) return;
    int l = g & 63;
    int rest = g >> 6;
    int nf = rest & 7;
    int kk = rest >> 3;
    int ci0 = kk * 32 + (l >> 4) * 8;
    int co = nf * 16 + (l & 15);
    union { unsigned short u[8]; int4 v; } out;
#pragma unroll
    for (int j = 0; j < 8; ++j)
        out.u[j] = f2bf(W3[(size_t)(ci0 + j) * CCH + co]);
    *(int4*)(W3f + (size_t)g * 8) = out.v;
}

// ---------------------------------------------------------------------------
// Kernel 2: conv1 via MFMA. 128 vox x 128 ch per block, K = 7 steps of 32.
// ---------------------------------------------------------------------------
__global__ __launch_bounds__(256) void conv1_mfma(
    const unsigned short* __restrict__ xeb, const int* __restrict__ nidx,
    const unsigned short* __restrict__ W1f, const float* __restrict__ b1,
    unsigned short* __restrict__ h1b) {
    __shared__ int4 bufmem[2048];
    __shared__ int idxAll[128 * 28];

    int tid = threadIdx.x;
    int l = tid & 63, w = tid >> 6;
    int mw = w >> 1, nwv = w & 1;
    int wg = xcd_swz(blockIdx.x, gridDim.x);
    int v0 = wg * 128;

    for (int g = tid; g < KOFF * 128; g += 256) {
        int k = g >> 7, vi = g & 127;
        int v = v0 + vi;
        idxAll[vi * 28 + k] = (v < N_VOX) ? nidx[(size_t)k * N_VOX + v] : N_VOX;
    }
    if (tid < 128) idxAll[tid * 28 + 27] = N_VOX;
    __syncthreads();

    f32x4 acc[4][4];
#pragma unroll
    for (int m = 0; m < 4; ++m)
#pragma unroll
        for (int n = 0; n < 4; ++n) acc[m][n] = (f32x4)0.f;

    {
        int4 g0[2]; int rr[2], cc[2];
#pragma unroll
        for (int u = 0; u < 2; ++u) {
            int q = u * 256 + tid;
            int r = q >> 2, oo = q & 3;
            int idx = idxAll[r * 28 + oo];
            g0[u] = *(const int4*)(xeb + (size_t)idx * 8);
            rr[u] = r; cc[u] = oo ^ (r & 3);
        }
#pragma unroll
        for (int u = 0; u < 2; ++u) bufmem[rr[u] * 5 + cc[u]] = g0[u];
    }
    __syncthreads();

    for (int kk = 0; kk < 7; ++kk) {
        int cur = kk & 1;
        int4 gg[2]; int rr[2], cc[2];
        if (kk < 6) {
#pragma unroll
            for (int u = 0; u < 2; ++u) {
                int q = u * 256 + tid;
                int r = q >> 2, oo = q & 3;
                int idx = idxAll[r * 28 + (kk + 1) * 4 + oo];
                gg[u] = *(const int4*)(xeb + (size_t)idx * 8);
                rr[u] = r; cc[u] = oo ^ (r & 3);
            }
        }
        bf16x8 a[4], b[4];
#pragma unroll
        for (int n = 0; n < 4; ++n) {
            int nf = nwv * 4 + n;
            b[n] = *(const bf16x8*)(W1f + ((size_t)(kk * 8 + nf) * 64 + l) * 8);
        }
#pragma unroll
        for (int m = 0; m < 4; ++m) {
            int r = mw * 64 + m * 16 + (l & 15);
            int c = l >> 4;
            a[m] = *(const bf16x8*)&bufmem[cur * 640 + r * 5 + (c ^ (r & 3))];
        }
#pragma unroll
        for (int m = 0; m < 4; ++m)
#pragma unroll
            for (int n = 0; n < 4; ++n)
                acc[m][n] = __builtin_amdgcn_mfma_f32_16x16x32_bf16(
                    a[m], b[n], acc[m][n], 0, 0, 0);
        if (kk < 6) {
#pragma unroll
            for (int u = 0; u < 2; ++u)
                bufmem[(cur ^ 1) * 640 + rr[u] * 5 + cc[u]] = gg[u];
        }
        __syncthreads();
    }

    float bias[4];
#pragma unroll
    for (int n = 0; n < 4; ++n) bias[n] = b1[nwv * 64 + n * 16 + (l & 15)];
    unsigned short* H16 = (unsigned short*)bufmem;
#pragma unroll
    for (int m = 0; m < 4; ++m) {
        int rbase = mw * 64 + m * 16 + (l >> 4) * 4;
#pragma unroll
        for (int n = 0; n < 4; ++n) {
            int ch = nwv * 64 + n * 16 + (l & 15);
            int c = ch >> 3;
            f32x4 d = acc[m][n];
#pragma unroll
            for (int ri = 0; ri < 4; ++ri) {
                int r = rbase + ri;
                int s = (c & 8) | ((c & 7) ^ (r & 7));
                H16[r * 128 + s * 8 + (ch & 7)] = f2bf(silu_f(d[ri] + bias[n]));
            }
        }
    }
    __syncthreads();
#pragma unroll
    for (int u = 0; u < 8; ++u) {
        int q = u * 256 + tid;
        int r = q >> 4, s = q & 15;
        int c = (s & 8) | ((s & 7) ^ (r & 7));
        int v = v0 + r;
        if (v < N_VOX)
            *(int4*)(h1b + (size_t)v * CCH + c * 8) = bufmem[r * 16 + s];
    }
    if (blockIdx.x == 0 && tid < 16)
        *(int4*)(h1b + (size_t)N_VOX * CCH + tid * 8) = make_int4(0, 0, 0, 0);
}

// ---------------------------------------------------------------------------
// Kernel 3: conv2 SPARSE + fused tail. Density 9.5% -> avg 3.4/27 neighbors
// active. Per block: ballot-compact per-offset active lists; center offset
// dense from registers; each sparse offset = gather <=32 compact rows ->
// 8KB LDS -> M=32 GEMM (16 MFMA/wave) -> P[32x128] -> mask-driven
// scatter-add into resident acc. MFMA/wave: 1728 -> ~480.
// LDS map (smem bytes): [0,8K) A32 | [8K,26.4K) P f32[128*36] |
//   [32K, 32K+6.9K) jlist[27][64] | masks/bases/cnt after.
//   Tail reuses [0,32K) as H16. Total ~40.5 KB -> 3 blocks/CU.
// ---------------------------------------------------------------------------
#define SMEM_P     8192
#define SMEM_BK    32768
#define PSTRIDE    36

#define SCATTER(KK, C2) {                                                  \
    const float* _Pf = (const float*)(smem + SMEM_P);                      \
    unsigned _w0 = maskL[(KK) * 4 + 2 * mw];                               \
    unsigned _w1 = maskL[(KK) * 4 + 2 * mw + 1];                           \
    unsigned _b0 = baseL[(KK) * 4 + 2 * mw];                               \
    unsigned _b1 = baseL[(KK) * 4 + 2 * mw + 1];                           \
    int _lo4 = (l >> 4) * 4;                                               \
    _Pragma("unroll")                                                      \
    for (int _m = 0; _m < 4; ++_m) {                                       \
        unsigned _wd = (_m < 2) ? _w0 : _w1;                               \
        unsigned _bs = (_m < 2) ? _b0 : _b1;                               \
        int _sh = (_m & 1) * 16 + _lo4;                                    \
        _Pragma("unroll")                                                  \
        for (int _ri = 0; _ri < 4; ++_ri) {                                \
            if ((_wd >> (_sh + _ri)) & 1u) {                               \
                int _p = _bs +                                             \
                    __popc(_wd & ((1u << (_sh + _ri)) - 1u));              \
                int _pr = _p - (C2) * 32;                                  \
                if (_pr >= 0 && _pr < 32) {                                \
                    _Pragma("unroll")                                      \
                    for (int _n = 0; _n < 4; ++_n) {                       \
                        int _ch = nwv * 64 + _n * 16 + (l & 15);           \
                        acc[_m][_n][_ri] += _Pf[_ch * PSTRIDE + _pr];      \
                    }                                                      \
                }                                                          \
            }                                                              \
        }                                                                  \
    }                                                                      \
}

__global__ __launch_bounds__(256, 3) void conv2_mfma(
    const unsigned short* __restrict__ h1b, const int* __restrict__ nidx,
    const unsigned short* __restrict__ W2f, const float* __restrict__ b2,
    const unsigned short* __restrict__ W3f, const float* __restrict__ b3,
    const float* __restrict__ W4, const float* __restrict__ b4,
    float* __restrict__ out) {
    __shared__ char smem[SMEM_BK + 6912 + 432 + 432 + 112];

    int* jlistL      = (int*)(smem + SMEM_BK);
    unsigned* maskL  = (unsigned*)(smem + SMEM_BK + 6912);
    unsigned* baseL  = maskL + KOFF * 4;
    int* cntL        = (int*)(baseL + KOFF * 4);

    int tid = threadIdx.x;
    int l = tid & 63, w = tid >> 6;
    int mw = w >> 1, nwv = w & 1;
    int wg = xcd_swz(blockIdx.x, gridDim.x);
    int v0 = wg * 128;

    // ---- bookkeeping: compact active lists per offset ----
    for (int i = tid; i < KOFF * 64; i += 256) jlistL[i] = N_VOX;
    __syncthreads();
    for (int k = w; k < KOFF; k += 4) {
        int v1 = v0 + l, v2 = v0 + 64 + l;
        int j1 = (v1 < N_VOX) ? nidx[(size_t)k * N_VOX + v1] : N_VOX;
        int j2 = (v2 < N_VOX) ? nidx[(size_t)k * N_VOX + v2] : N_VOX;
        bool f1 = (k != 13) && (j1 != N_VOX);
        bool f2 = (k != 13) && (j2 != N_VOX);
        unsigned long long bal1 = __ballot(f1);
        unsigned long long bal2 = __ballot(f2);
        unsigned long long lt = ((unsigned long long)1 << l) - 1;
        int p1 = __popcll(bal1 & lt);
        int p2 = __popcll(bal1) + __popcll(bal2 & lt);
        if (f1 && p1 < 64) jlistL[k * 64 + p1] = j1;
        if (f2 && p2 < 64) jlistL[k * 64 + p2] = j2;
        if (l == 0) {
            unsigned m0 = (unsigned)bal1, m1 = (unsigned)(bal1 >> 32);
            unsigned m2 = (unsigned)bal2, m3 = (unsigned)(bal2 >> 32);
            maskL[k * 4 + 0] = m0; maskL[k * 4 + 1] = m1;
            maskL[k * 4 + 2] = m2; maskL[k * 4 + 3] = m3;
            unsigned c0 = __popc(m0), c1 = __popc(m1), c2 = __popc(m2);
            baseL[k * 4 + 0] = 0;
            baseL[k * 4 + 1] = c0;
            baseL[k * 4 + 2] = c0 + c1;
            baseL[k * 4 + 3] = c0 + c1 + c2;
            cntL[k] = c0 + c1 + c2 + __popc(m3);
        }
    }
    __syncthreads();

    // ---- dense center offset k=13 (self rows, no gather) ----
    f32x4 acc[4][4];
#pragma unroll
    for (int m = 0; m < 4; ++m)
#pragma unroll
        for (int n = 0; n < 4; ++n) acc[m][n] = (f32x4)0.f;
    {
        const unsigned short* wb = W2f + (size_t)13 * 16384;
#pragma unroll
        for (int kk = 0; kk < 4; ++kk) {
            bf16x8 a[4], b[4];
#pragma unroll
            for (int m = 0; m < 4; ++m) {
                int v = v0 + mw * 64 + m * 16 + (l & 15);
                if (v >= N_VOX) v = N_VOX;
                a[m] = *(const bf16x8*)(h1b + (size_t)v * CCH +
                                        kk * 32 + (l >> 4) * 8);
            }
#pragma unroll
            for (int n = 0; n < 4; ++n)
                b[n] = *(const bf16x8*)(wb +
                    ((size_t)(kk * 8 + nwv * 4 + n) * 64 + l) * 8);
#pragma unroll
            for (int m = 0; m < 4; ++m)
#pragma unroll
                for (int n = 0; n < 4; ++n)
                    acc[m][n] = __builtin_amdgcn_mfma_f32_16x16x32_bf16(
                        a[m], b[n], acc[m][n], 0, 0, 0);
        }
    }

    // ---- sparse offsets ----
    float* Pf = (float*)(smem + SMEM_P);
    int pk = -1, pc2 = 0;
    for (int k = 0; k < KOFF; ++k) {
        int cnt = cntL[k];
        if (cnt == 0) continue;            // block-uniform (incl. k=13)
        int nch = (cnt + 31) >> 5;
        if (nch > 2) nch = 2;
        for (int c2 = 0; c2 < nch; ++c2) {
            // (a) stage compact A rows (regions R = w*2+uu of frag-tiled A32)
#pragma unroll
            for (int uu = 0; uu < 2; ++uu) {
                int R = w * 2 + uu, mc = R >> 2, ks = R & 3;
                int slot = c2 * 32 + mc * 16 + (l & 15);
                int j = jlistL[k * 64 + slot];
                gload_lds16((const char*)h1b + (size_t)j * 256 +
                                ks * 64 + (l >> 4) * 16,
                            smem + (size_t)(R * 64 + l) * 16);
            }
            // (b) B frags for this offset (wave covers cols [w*32, w*32+32))
            bf16x8 bfr[4][2];
            {
                const unsigned short* wb = W2f + (size_t)k * 16384;
#pragma unroll
                for (int ks = 0; ks < 4; ++ks)
#pragma unroll
                    for (int nc = 0; nc < 2; ++nc)
                        bfr[ks][nc] = *(const bf16x8*)(wb +
                            ((size_t)(ks * 8 + w * 2 + nc) * 64 + l) * 8);
            }
            // (g') scatter previous P while stage is in flight
            if (pk >= 0) { SCATTER(pk, pc2); }
            __syncthreads();   // stage done (drains vmcnt), P consumed
            // (d) compact M=32 GEMM
            f32x4 accc[2][2];
#pragma unroll
            for (int mc = 0; mc < 2; ++mc)
#pragma unroll
                for (int nc = 0; nc < 2; ++nc) accc[mc][nc] = (f32x4)0.f;
#pragma unroll
            for (int ks = 0; ks < 4; ++ks) {
                bf16x8 a2[2];
#pragma unroll
                for (int mc = 0; mc < 2; ++mc)
                    a2[mc] = *(const bf16x8*)(smem +
                        (size_t)((mc * 4 + ks) * 64 + l) * 16);
#pragma unroll
                for (int mc = 0; mc < 2; ++mc)
#pragma unroll
                    for (int nc = 0; nc < 2; ++nc)
                        accc[mc][nc] = __builtin_amdgcn_mfma_f32_16x16x32_bf16(
                            a2[mc], bfr[ks][nc], accc[mc][nc], 0, 0, 0);
            }
            // (e) write P col-major stride 36 (16B-aligned, ~2-way free)
#pragma unroll
            for (int mc = 0; mc < 2; ++mc)
#pragma unroll
                for (int nc = 0; nc < 2; ++nc) {
                    int col = w * 32 + nc * 16 + (l & 15);
                    int prow = mc * 16 + (l >> 4) * 4;
                    *(f32x4*)&Pf[col * PSTRIDE + prow] = accc[mc][nc];
                }
            __syncthreads();
            pk = k; pc2 = c2;
        }
    }
    if (pk >= 0) { SCATTER(pk, pc2); }
    __syncthreads();

    // ---- fused tail: H = bf16(silu(acc+b2)) -> LDS; P = H @ W3; out ----
    float bias2[4];
#pragma unroll
    for (int n = 0; n < 4; ++n) bias2[n] = b2[nwv * 64 + n * 16 + (l & 15)];
    unsigned short* H16 = (unsigned short*)smem;
#pragma unroll
    for (int m = 0; m < 4; ++m) {
        int rbase = mw * 64 + m * 16 + (l >> 4) * 4;
#pragma unroll
        for (int n = 0; n < 4; ++n) {
            int ch = nwv * 64 + n * 16 + (l & 15);
            int c = ch >> 3;
            f32x4 d = acc[m][n];
#pragma unroll
            for (int ri = 0; ri < 4; ++ri) {
                int r = rbase + ri;
                int s = (c & 8) | ((c & 7) ^ (r & 7));
                H16[r * 128 + s * 8 + (ch & 7)] = f2bf(silu_f(d[ri] + bias2[n]));
            }
        }
    }
    __syncthreads();

    f32x4 p[4][4];
#pragma unroll
    for (int m = 0; m < 4; ++m)
#pragma unroll
        for (int n = 0; n < 4; ++n) p[m][n] = (f32x4)0.f;
#pragma unroll
    for (int kk = 0; kk < 4; ++kk) {
        bf16x8 a[4], b[4];
#pragma unroll
        for (int n = 0; n < 4; ++n) {
            int nf = nwv * 4 + n;
            b[n] = *(const bf16x8*)(W3f + ((size_t)(kk * 8 + nf) * 64 + l) * 8);
        }
#pragma unroll
        for (int m = 0; m < 4; ++m) {
            int r = mw * 64 + m * 16 + (l & 15);
            int c = kk * 4 + (l >> 4);
            int s = (c & 8) | ((c & 7) ^ (r & 7));
            a[m] = *(const bf16x8*)&H16[r * 128 + s * 8];
        }
#pragma unroll
        for (int m = 0; m < 4; ++m)
#pragma unroll
            for (int n = 0; n < 4; ++n)
                p[m][n] = __builtin_amdgcn_mfma_f32_16x16x32_bf16(
                    a[m], b[n], p[m][n], 0, 0, 0);
    }

    float w4v[4], b3v[4];
#pragma unroll
    for (int n = 0; n < 4; ++n) {
        int ch = nwv * 64 + n * 16 + (l & 15);
        w4v[n] = W4[ch];
        b3v[n] = b3[ch];
    }
    float* Osum = (float*)jlistL;
#pragma unroll
    for (int m = 0; m < 4; ++m) {
        float po[4] = {0.f, 0.f, 0.f, 0.f};
#pragma unroll
        for (int n = 0; n < 4; ++n) {
            f32x4 d = p[m][n];
#pragma unroll
            for (int ri = 0; ri < 4; ++ri)
                po[ri] += silu_f(d[ri] + b3v[n]) * w4v[n];
        }
#pragma unroll
        for (int off = 1; off < 16; off <<= 1)
#pragma unroll
            for (int ri = 0; ri < 4; ++ri)
                po[ri] += __shfl_xor(po[ri], off, 64);
        if ((l & 15) == 0) {
            int rbase = mw * 64 + m * 16 + (l >> 4) * 4;
#pragma unroll
            for (int ri = 0; ri < 4; ++ri)
                Osum[nwv * 128 + rbase + ri] = po[ri];
        }
    }
    __syncthreads();
    if (tid < 128) {
        int v = v0 + tid;
        if (v < N_VOX) out[v] = Osum[tid] + Osum[128 + tid] + b4[0];
    }
}

// ---------------------------------------------------------------------------
extern "C" void kernel_launch(void* const* d_in, const int* in_sizes, int n_in,
                              void* d_out, int out_size, void* d_ws,
                              size_t ws_size, hipStream_t stream) {
    const float* feat = (const float*)d_in[0];
    const int* t      = (const int*)d_in[1];
    const int* nidx   = (const int*)d_in[2];
    const float* W1   = (const float*)d_in[3];
    const float* b1   = (const float*)d_in[4];
    const float* W2   = (const float*)d_in[5];
    const float* b2   = (const float*)d_in[6];
    const float* W3   = (const float*)d_in[7];
    const float* b3   = (const float*)d_in[8];
    const float* W4   = (const float*)d_in[9];
    const float* b4   = (const float*)d_in[10];
    float* out = (float*)d_out;

    char* ws = (char*)d_ws;
    size_t off = 0;
    unsigned short* xeb = (unsigned short*)(ws + off);
    off += ((size_t)(N_VOX + 1) * 8 * 2 + 255) & ~(size_t)255;
    unsigned short* h1b = (unsigned short*)(ws + off);
    off += ((size_t)(N_VOX + 1) * CCH * 2 + 255) & ~(size_t)255;
    unsigned short* W1f = (unsigned short*)(ws + off);
    off += ((size_t)7 * 8 * 64 * 8 * 2 + 255) & ~(size_t)255;
    unsigned short* W2f = (unsigned short*)(ws + off);
    off += ((size_t)(KOFF + 1) * 4 * 8 * 64 * 8 * 2 + 255) & ~(size_t)255;
    unsigned short* W3f = (unsigned short*)(ws + off);

    int grid1 = (N_VOX + 127) / 128;
    int grid2 = (N_VOX + 127) / 128;
    embed_kernel<<<(N_VOX + 1 + 255) / 256, 256, 0, stream>>>(feat, t, xeb);
    convert_w1<<<(7 * 8 * 64 + 255) / 256, 256, 0, stream>>>(W1, W1f);
    convert_w2<<<(KOFF * 4 * 8 * 64) / 256, 256, 0, stream>>>(W2, W2f);
    convert_w3<<<(4 * 8 * 64 + 255) / 256, 256, 0, stream>>>(W3, W3f);
    conv1_mfma<<<grid1, 256, 0, stream>>>(xeb, nidx, W1f, b1, h1b);
    conv2_mfma<<<grid2, 256, 0, stream>>>(h1b, nidx, W2f, b2, W3f, b3, W4, b4, out);
}

// Round 12
// 277.259 us; speedup vs baseline: 1.1243x; 1.0996x over previous
//
#include <hip/hip_runtime.h>
#include <math.h>

#define N_VOX 200000
#define CCH   128
#define KOFF  27

typedef __attribute__((ext_vector_type(8))) short bf16x8;
typedef __attribute__((ext_vector_type(4))) float f32x4;

__device__ __forceinline__ float silu_f(float x) {
    return x / (1.0f + expf(-x));
}
__device__ __forceinline__ unsigned short f2bf(float x) {
    unsigned int u = __float_as_uint(x);
    u = (u + 0x7FFFu + ((u >> 16) & 1u)) >> 16;
    return (unsigned short)u;
}
// bijective XCD-aware block swizzle (m204 variant)
__device__ __forceinline__ int xcd_swz(int orig, int nwg) {
    int q = nwg >> 3, r = nwg & 7;
    int xcd = orig & 7, pos = orig >> 3;
    return (xcd < r ? xcd * (q + 1) : r * (q + 1) + (xcd - r) * q) + pos;
}
// async 16B global -> LDS (direct-to-shared DMA)
__device__ __forceinline__ void gload_lds16(const void* g, void* l) {
    __builtin_amdgcn_global_load_lds(
        (const __attribute__((address_space(1))) unsigned int*)g,
        (__attribute__((address_space(3))) unsigned int*)l, 16, 0, 0);
}

// ---------------------------------------------------------------------------
// Kernel 1: time embedding -> bf16 xeb[(N+1)][8] = {feat, sin*3, cos*3, 0}
// ---------------------------------------------------------------------------
__global__ void embed_kernel(const float* __restrict__ feat,
                             const int* __restrict__ t,
                             unsigned short* __restrict__ xeb) {
    int i = blockIdx.x * blockDim.x + threadIdx.x;
    if (i > N_VOX) return;
    union { unsigned short u[8]; int4 v; } o;
    if (i == N_VOX) {
        o.v = make_int4(0, 0, 0, 0);
    } else {
        o.u[0] = f2bf(feat[i]);
        float tf = (float)t[i];
#pragma unroll
        for (int kk = 0; kk < 3; ++kk) {
            float freq = (float)M_PI * (float)(1 << kk);
            float ang = tf * freq;
            o.u[1 + kk] = f2bf(sinf(ang));
            o.u[4 + kk] = f2bf(cosf(ang));
        }
        o.u[7] = 0;
    }
    *(int4*)(xeb + (size_t)i * 8) = o.v;
}

// ---------------------------------------------------------------------------
// Weight repacks to MFMA-fragment-linear bf16 (B-operand layout).
// ---------------------------------------------------------------------------
__global__ void convert_w1(const float* __restrict__ W1,
                           unsigned short* __restrict__ W1f) {
    int g = blockIdx.x * 256 + threadIdx.x;
    if (g >= 7 * 8 * 64) return;
    int l = g & 63;
    int rest = g >> 6;
    int nf = rest & 7;
    int kk = rest >> 3;
    int o = kk * 4 + (l >> 4);
    int co = nf * 16 + (l & 15);
    union { unsigned short u[8]; int4 v; } out;
#pragma unroll
    for (int j = 0; j < 8; ++j) {
        float w = 0.f;
        if (o < KOFF && j < 7) w = W1[((size_t)o * 7 + j) * CCH + co];
        out.u[j] = f2bf(w);
    }
    *(int4*)(W1f + (size_t)g * 8) = out.v;
}

__global__ void convert_w2(const float* __restrict__ W2,
                           unsigned short* __restrict__ W2f) {
    int g = blockIdx.x * 256 + threadIdx.x;
    int l = g & 63;
    int rest = g >> 6;
    int nf = rest & 7;
    int kkk = rest >> 3;
    int k = kkk >> 2, kk = kkk & 3;
    int ci0 = kk * 32 + (l >> 4) * 8;
    int co = nf * 16 + (l & 15);
    union { unsigned short u[8]; int4 v; } out;
#pragma unroll
    for (int j = 0; j < 8; ++j)
        out.u[j] = f2bf(W2[((size_t)k * CCH + ci0 + j) * CCH + co]);
    *(int4*)(W2f + (size_t)g * 8) = out.v;
}

__global__ void convert_w3(const float* __restrict__ W3,
                           unsigned short* __restrict__ W3f) {
    int g = blockIdx.x * 256 + threadIdx.x;
    if (g >= 4 * 8 * 64) return;
    int l = g & 63;
    int rest = g >> 6;
    int nf = rest & 7;
    int kk = rest >> 3;
    int ci0 = kk * 32 + (l >> 4) * 8;
    int co = nf * 16 + (l & 15);
    union { unsigned short u[8]; int4 v; } out;
#pragma unroll
    for (int j = 0; j < 8; ++j)
        out.u[j] = f2bf(W3[(size_t)(ci0 + j) * CCH + co]);
    *(int4*)(W3f + (size_t)g * 8) = out.v;
}

// ---------------------------------------------------------------------------
// Kernel 2: conv1 via MFMA. 128 vox x 128 ch per block, K = 7 steps of 32.
// ---------------------------------------------------------------------------
__global__ __launch_bounds__(256) void conv1_mfma(
    const unsigned short* __restrict__ xeb, const int* __restrict__ nidx,
    const unsigned short* __restrict__ W1f, const float* __restrict__ b1,
    unsigned short* __restrict__ h1b) {
    __shared__ int4 bufmem[2048];
    __shared__ int idxAll[128 * 28];

    int tid = threadIdx.x;
    int l = tid & 63, w = tid >> 6;
    int mw = w >> 1, nwv = w & 1;
    int wg = xcd_swz(blockIdx.x, gridDim.x);
    int v0 = wg * 128;

    for (int g = tid; g < KOFF * 128; g += 256) {
        int k = g >> 7, vi = g & 127;
        int v = v0 + vi;
        idxAll[vi * 28 + k] = (v < N_VOX) ? nidx[(size_t)k * N_VOX + v] : N_VOX;
    }
    if (tid < 128) idxAll[tid * 28 + 27] = N_VOX;
    __syncthreads();

    f32x4 acc[4][4];
#pragma unroll
    for (int m = 0; m < 4; ++m)
#pragma unroll
        for (int n = 0; n < 4; ++n) acc[m][n] = (f32x4)0.f;

    {
        int4 g0[2]; int rr[2], cc[2];
#pragma unroll
        for (int u = 0; u < 2; ++u) {
            int q = u * 256 + tid;
            int r = q >> 2, oo = q & 3;
            int idx = idxAll[r * 28 + oo];
            g0[u] = *(const int4*)(xeb + (size_t)idx * 8);
            rr[u] = r; cc[u] = oo ^ (r & 3);
        }
#pragma unroll
        for (int u = 0; u < 2; ++u) bufmem[rr[u] * 5 + cc[u]] = g0[u];
    }
    __syncthreads();

    for (int kk = 0; kk < 7; ++kk) {
        int cur = kk & 1;
        int4 gg[2]; int rr[2], cc[2];
        if (kk < 6) {
#pragma unroll
            for (int u = 0; u < 2; ++u) {
                int q = u * 256 + tid;
                int r = q >> 2, oo = q & 3;
                int idx = idxAll[r * 28 + (kk + 1) * 4 + oo];
                gg[u] = *(const int4*)(xeb + (size_t)idx * 8);
                rr[u] = r; cc[u] = oo ^ (r & 3);
            }
        }
        bf16x8 a[4], b[4];
#pragma unroll
        for (int n = 0; n < 4; ++n) {
            int nf = nwv * 4 + n;
            b[n] = *(const bf16x8*)(W1f + ((size_t)(kk * 8 + nf) * 64 + l) * 8);
        }
#pragma unroll
        for (int m = 0; m < 4; ++m) {
            int r = mw * 64 + m * 16 + (l & 15);
            int c = l >> 4;
            a[m] = *(const bf16x8*)&bufmem[cur * 640 + r * 5 + (c ^ (r & 3))];
        }
#pragma unroll
        for (int m = 0; m < 4; ++m)
#pragma unroll
            for (int n = 0; n < 4; ++n)
                acc[m][n] = __builtin_amdgcn_mfma_f32_16x16x32_bf16(
                    a[m], b[n], acc[m][n], 0, 0, 0);
        if (kk < 6) {
#pragma unroll
            for (int u = 0; u < 2; ++u)
                bufmem[(cur ^ 1) * 640 + rr[u] * 5 + cc[u]] = gg[u];
        }
        __syncthreads();
    }

    float bias[4];
#pragma unroll
    for (int n = 0; n < 4; ++n) bias[n] = b1[nwv * 64 + n * 16 + (l & 15)];
    unsigned short* H16 = (unsigned short*)bufmem;
#pragma unroll
    for (int m = 0; m < 4; ++m) {
        int rbase = mw * 64 + m * 16 + (l >> 4) * 4;
#pragma unroll
        for (int n = 0; n < 4; ++n) {
            int ch = nwv * 64 + n * 16 + (l & 15);
            int c = ch >> 3;
            f32x4 d = acc[m][n];
#pragma unroll
            for (int ri = 0; ri < 4; ++ri) {
                int r = rbase + ri;
                int s = (c & 8) | ((c & 7) ^ (r & 7));
                H16[r * 128 + s * 8 + (ch & 7)] = f2bf(silu_f(d[ri] + bias[n]));
            }
        }
    }
    __syncthreads();
#pragma unroll
    for (int u = 0; u < 8; ++u) {
        int q = u * 256 + tid;
        int r = q >> 4, s = q & 15;
        int c = (s & 8) | ((s & 7) ^ (r & 7));
        int v = v0 + r;
        if (v < N_VOX)
            *(int4*)(h1b + (size_t)v * CCH + c * 8) = bufmem[r * 16 + s];
    }
    if (blockIdx.x == 0 && tid < 16)
        *(int4*)(h1b + (size_t)N_VOX * CCH + tid * 8) = make_int4(0, 0, 0, 0);
}

// ---------------------------------------------------------------------------
// Kernel 3: conv2, BM=256 / per-wave 128x64 (acc[8][4] = 128 VGPR) to HALVE
// B-fragment L2 traffic per voxel (B/vox = 32KB/M_wave). 54 BK=64 steps,
// double-buffered 32KB frag-tiled A-tiles (zero-conflict lane-linear
// ds_read_b128), round-7 T3-min schedule per step:
//   B(8) -> STAGE(next, 8 gload_lds) [-> idx(k+1) on even steps]
//   -> 64 MFMA -> vmcnt(0) -> s_barrier.
// LDS = 64K A + 2K idx + 2K Osum = 68 KB -> 2 blocks/CU.
// ---------------------------------------------------------------------------
#define STAGE_S(buf, sq, ib) {                                             \
    _Pragma("unroll") for (int _u = 0; _u < 8; ++_u) {                     \
        int _q = _u * 256 + tid;                                           \
        int _row = ((_q >> 7) << 4) | (_q & 15);                           \
        int _hi = (_q >> 4) & 3;                                           \
        int _kk = (_q >> 6) & 1;                                           \
        int _idx = idxbuf[ib][_row];                                       \
        gload_lds16((const char*)h1b + ((size_t)(unsigned)_idx << 8) +     \
                        ((sq) & 1) * 128 + _kk * 64 + _hi * 16,            \
                    (void*)&Abuf[buf][_q]);                                \
    }                                                                      \
}

#define LOADB_S(dst, sq) {                                                 \
    const unsigned short* _wb = W2f + (size_t)((sq) >> 1) * 16384 +        \
                                (size_t)((sq) & 1) * 2 * 4096;             \
    _Pragma("unroll") for (int _kk = 0; _kk < 2; ++_kk)                    \
        _Pragma("unroll") for (int _n = 0; _n < 4; ++_n)                   \
            dst[_kk][_n] = *(const bf16x8*)(_wb +                          \
                ((size_t)(_kk * 8 + nwv * 4 + _n) * 64 + l) * 8);          \
}

#define MFMA_S(cur, bfr) {                                                 \
    _Pragma("unroll") for (int _kk = 0; _kk < 2; ++_kk) {                  \
        bf16x8 _a[8];                                                      \
        _Pragma("unroll") for (int _m = 0; _m < 8; ++_m) {                 \
            int _R = mw * 8 + _m;                                          \
            _a[_m] = *(const bf16x8*)&Abuf[cur][((_R * 2 + _kk) << 6) + l];\
        }                                                                  \
        __builtin_amdgcn_s_setprio(1);                                     \
        _Pragma("unroll") for (int _m = 0; _m < 8; ++_m)                   \
            _Pragma("unroll") for (int _n = 0; _n < 4; ++_n)               \
                acc[_m][_n] = __builtin_amdgcn_mfma_f32_16x16x32_bf16(     \
                    _a[_m], bfr[_kk][_n], acc[_m][_n], 0, 0, 0);           \
        __builtin_amdgcn_s_setprio(0);                                     \
    }                                                                      \
}

#define STEP_S(SQ, CUR, DO_STAGE, DO_IDX) {                                \
    bf16x8 bfr[2][4];                                                      \
    LOADB_S(bfr, SQ);                                                      \
    __builtin_amdgcn_sched_barrier(0);                                     \
    if (DO_STAGE) { STAGE_S((CUR) ^ 1, (SQ) + 1, ((((SQ) + 1) >> 1) & 1)); }\
    if (DO_IDX) {                                                          \
        int _k1 = ((SQ) >> 1) + 1;                                         \
        int _v = v0 + tid;                                                 \
        idxbuf[_k1 & 1][tid] =                                             \
            (_v < N_VOX) ? nidx[(size_t)_k1 * N_VOX + _v] : N_VOX;         \
    }                                                                      \
    __builtin_amdgcn_sched_barrier(0);                                     \
    MFMA_S(CUR, bfr);                                                      \
    asm volatile("s_waitcnt vmcnt(0)" ::: "memory");                       \
    __builtin_amdgcn_s_barrier();                                          \
}

__global__ __launch_bounds__(256, 2) void conv2_mfma(
    const unsigned short* __restrict__ h1b, const int* __restrict__ nidx,
    const unsigned short* __restrict__ W2f, const float* __restrict__ b2,
    const unsigned short* __restrict__ W3f, const float* __restrict__ b3,
    const float* __restrict__ W4, const float* __restrict__ b4,
    float* __restrict__ out) {
    __shared__ int4 Abuf[2][2048];   // 64 KB, frag-tiled BK=64 A-tiles
    __shared__ int idxbuf[2][256];   // 2 KB, per-k gather indices
    __shared__ float Osum[512];      // 2 KB tail reduce

    int tid = threadIdx.x;
    int l = tid & 63, w = tid >> 6;
    int mw = w >> 1, nwv = w & 1;
    int wg = xcd_swz(blockIdx.x, gridDim.x);
    int v0 = wg * 256;

    f32x4 acc[8][4];
#pragma unroll
    for (int m = 0; m < 8; ++m)
#pragma unroll
        for (int n = 0; n < 4; ++n) acc[m][n] = (f32x4)0.f;

    // prologue: idx(k=0) -> sync -> stage step0 + idx(k=1) -> drain -> sync
    {
        int v = v0 + tid;
        idxbuf[0][tid] = (v < N_VOX) ? nidx[v] : N_VOX;
    }
    __syncthreads();
    STAGE_S(0, 0, 0);
    {
        int v = v0 + tid;
        idxbuf[1][tid] = (v < N_VOX) ? nidx[(size_t)N_VOX + v] : N_VOX;
    }
    asm volatile("s_waitcnt vmcnt(0)" ::: "memory");
    __syncthreads();

    for (int sp = 0; sp < 52; sp += 2) {
        STEP_S(sp, 0, true, ((sp >> 1) + 1 < KOFF));
        STEP_S(sp + 1, 1, true, false);
    }
    STEP_S(52, 0, true, false);    // stages step 53
    STEP_S(53, 1, false, false);   // last: no staging

    // ---- fused tail: H = bf16(silu(acc+b2)) -> LDS; P = H @ W3; out ----
    float bias2[4];
#pragma unroll
    for (int n = 0; n < 4; ++n) bias2[n] = b2[nwv * 64 + n * 16 + (l & 15)];
    unsigned short* H16 = (unsigned short*)&Abuf[0][0];   // 256x128 = 64 KB
#pragma unroll
    for (int m = 0; m < 8; ++m) {
        int rbase = mw * 128 + m * 16 + (l >> 4) * 4;
#pragma unroll
        for (int n = 0; n < 4; ++n) {
            int ch = nwv * 64 + n * 16 + (l & 15);
            int c = ch >> 3;
            f32x4 d = acc[m][n];
#pragma unroll
            for (int ri = 0; ri < 4; ++ri) {
                int r = rbase + ri;
                int s = (c & 8) | ((c & 7) ^ (r & 7));
                H16[r * 128 + s * 8 + (ch & 7)] = f2bf(silu_f(d[ri] + bias2[n]));
            }
        }
    }
    __syncthreads();

    f32x4 p[8][4];
#pragma unroll
    for (int m = 0; m < 8; ++m)
#pragma unroll
        for (int n = 0; n < 4; ++n) p[m][n] = (f32x4)0.f;
#pragma unroll
    for (int kk = 0; kk < 4; ++kk) {
        bf16x8 a[8], b[4];
#pragma unroll
        for (int n = 0; n < 4; ++n) {
            int nf = nwv * 4 + n;
            b[n] = *(const bf16x8*)(W3f + ((size_t)(kk * 8 + nf) * 64 + l) * 8);
        }
#pragma unroll
        for (int m = 0; m < 8; ++m) {
            int r = mw * 128 + m * 16 + (l & 15);
            int c = kk * 4 + (l >> 4);
            int s = (c & 8) | ((c & 7) ^ (r & 7));
            a[m] = *(const bf16x8*)&H16[r * 128 + s * 8];
        }
#pragma unroll
        for (int m = 0; m < 8; ++m)
#pragma unroll
            for (int n = 0; n < 4; ++n)
                p[m][n] = __builtin_amdgcn_mfma_f32_16x16x32_bf16(
                    a[m], b[n], p[m][n], 0, 0, 0);
    }

    float w4v[4], b3v[4];
#pragma unroll
    for (int n = 0; n < 4; ++n) {
        int ch = nwv * 64 + n * 16 + (l & 15);
        w4v[n] = W4[ch];
        b3v[n] = b3[ch];
    }
#pragma unroll
    for (int m = 0; m < 8; ++m) {
        float po[4] = {0.f, 0.f, 0.f, 0.f};
#pragma unroll
        for (int n = 0; n < 4; ++n) {
            f32x4 d = p[m][n];
#pragma unroll
            for (int ri = 0; ri < 4; ++ri)
                po[ri] += silu_f(d[ri] + b3v[n]) * w4v[n];
        }
#pragma unroll
        for (int off = 1; off < 16; off <<= 1)
#pragma unroll
            for (int ri = 0; ri < 4; ++ri)
                po[ri] += __shfl_xor(po[ri], off, 64);
        if ((l & 15) == 0) {
            int rbase = mw * 128 + m * 16 + (l >> 4) * 4;
#pragma unroll
            for (int ri = 0; ri < 4; ++ri)
                Osum[nwv * 256 + rbase + ri] = po[ri];
        }
    }
    __syncthreads();
    {
        int v = v0 + tid;
        if (v < N_VOX) out[v] = Osum[tid] + Osum[256 + tid] + b4[0];
    }
}

// ---------------------------------------------------------------------------
extern "C" void kernel_launch(void* const* d_in, const int* in_sizes, int n_in,
                              void* d_out, int out_size, void* d_ws,
                              size_t ws_size, hipStream_t stream) {
    const float* feat = (const float*)d_in[0];
    const int* t      = (const int*)d_in[1];
    const int* nidx   = (const int*)d_in[2];
    const float* W1   = (const float*)d_in[3];
    const float* b1   = (const float*)d_in[4];
    const float* W2   = (const float*)d_in[5];
    const float* b2   = (const float*)d_in[6];
    const float* W3   = (const float*)d_in[7];
    const float* b3   = (const float*)d_in[8];
    const float* W4   = (const float*)d_in[9];
    const float* b4   = (const float*)d_in[10];
    float* out = (float*)d_out;

    char* ws = (char*)d_ws;
    size_t off = 0;
    unsigned short* xeb = (unsigned short*)(ws + off);
    off += ((size_t)(N_VOX + 1) * 8 * 2 + 255) & ~(size_t)255;
    unsigned short* h1b = (unsigned short*)(ws + off);
    off += ((size_t)(N_VOX + 1) * CCH * 2 + 255) & ~(size_t)255;
    unsigned short* W1f = (unsigned short*)(ws + off);
    off += ((size_t)7 * 8 * 64 * 8 * 2 + 255) & ~(size_t)255;
    unsigned short* W2f = (unsigned short*)(ws + off);
    off += ((size_t)(KOFF + 1) * 4 * 8 * 64 * 8 * 2 + 255) & ~(size_t)255;
    unsigned short* W3f = (unsigned short*)(ws + off);

    int grid1 = (N_VOX + 127) / 128;
    int grid2 = (N_VOX + 255) / 256;
    embed_kernel<<<(N_VOX + 1 + 255) / 256, 256, 0, stream>>>(feat, t, xeb);
    convert_w1<<<(7 * 8 * 64 + 255) / 256, 256, 0, stream>>>(W1, W1f);
    convert_w2<<<(KOFF * 4 * 8 * 64) / 256, 256, 0, stream>>>(W2, W2f);
    convert_w3<<<(4 * 8 * 64 + 255) / 256, 256, 0, stream>>>(W3, W3f);
    conv1_mfma<<<grid1, 256, 0, stream>>>(xeb, nidx, W1f, b1, h1b);
    conv2_mfma<<<grid2, 256, 0, stream>>>(h1b, nidx, W2f, b2, W3f, b3, W4, b4, out);
}